// Round 5
// baseline (674.659 us; speedup 1.0000x reference)
//
#include <hip/hip_runtime.h>
#include <stdint.h>
#include <stddef.h>

#define BB 32
#define SS 2048
#define HH 1024
#define MTOT (BB*SS)   // 65536
#define NC 16          // context chunks per batch

typedef _Float16 h8 __attribute__((ext_vector_type(8)));
typedef float f32x4 __attribute__((ext_vector_type(4)));

__device__ __forceinline__ void gload_lds16(const void* g, void* l) {
  __builtin_amdgcn_global_load_lds(
      (const __attribute__((address_space(1))) void*)g,
      (__attribute__((address_space(3))) void*)l,
      16, 0, 0);
}

__device__ __forceinline__ float fast_tanh(float x) {
  x = fminf(15.f, fmaxf(-15.f, x));
  float t = __expf(2.f * x);
  return (t - 1.f) * __builtin_amdgcn_rcpf(t + 1.f);
}

// ---------------- fp32 -> fp16 streaming convert ----------------
// one-shot small version (Ua: 1M elems)
__global__ __launch_bounds__(256) void cvt_h(const float* __restrict__ src,
                                             _Float16* __restrict__ dst) {
  int t = blockIdx.x * 256 + threadIdx.x;
  const float4* s4 = (const float4*)src + (size_t)t * 2;
  float4 f0 = s4[0], f1 = s4[1];
  h8 v;
  v[0]=(_Float16)f0.x; v[1]=(_Float16)f0.y; v[2]=(_Float16)f0.z; v[3]=(_Float16)f0.w;
  v[4]=(_Float16)f1.x; v[5]=(_Float16)f1.y; v[6]=(_Float16)f1.z; v[7]=(_Float16)f1.w;
  *(h8*)(dst + (size_t)t * 8) = v;
}

// grid-strided big version (enc: 67.1M elems). 4096 blocks x 8 chunks;
// unrolled so 16 independent float4 loads are in flight per thread.
__global__ __launch_bounds__(256) void cvt_h_big(const float* __restrict__ src,
                                                 _Float16* __restrict__ dst) {
#pragma unroll
  for (int i = 0; i < 8; ++i) {
    size_t t = ((size_t)(blockIdx.x + 4096 * i)) * 256 + threadIdx.x;
    const float4* s4 = (const float4*)src + t * 2;
    float4 f0 = s4[0], f1 = s4[1];
    h8 v;
    v[0]=(_Float16)f0.x; v[1]=(_Float16)f0.y; v[2]=(_Float16)f0.z; v[3]=(_Float16)f0.w;
    v[4]=(_Float16)f1.x; v[5]=(_Float16)f1.y; v[6]=(_Float16)f1.z; v[7]=(_Float16)f1.w;
    *(h8*)(dst + t * 8) = v;
  }
}

// ---------------- qv[b,o] = dh[b,:]·Wa[o,:] + Wa_b[o] + Ua_b[o] ----------------
__global__ __launch_bounds__(256) void query_k(const float* __restrict__ dh,
                                               const float* __restrict__ Wa,
                                               const float* __restrict__ Wa_b,
                                               const float* __restrict__ Ua_b,
                                               float* __restrict__ qv) {
  int gw = (blockIdx.x * 256 + threadIdx.x) >> 6;   // wave id, 32768 total
  int lane = threadIdx.x & 63;
  int o = gw >> 5;                                  // o-major: Wa row reused by 32 waves
  int b = gw & 31;
  const float4* x4 = (const float4*)(dh + (size_t)b * HH);
  const float4* w4 = (const float4*)(Wa + (size_t)o * HH);
  float s = 0.f;
#pragma unroll
  for (int j = 0; j < 4; ++j) {
    float4 a = x4[lane + 64 * j];
    float4 c = w4[lane + 64 * j];
    s += a.x * c.x + a.y * c.y + a.z * c.z + a.w * c.w;
  }
#pragma unroll
  for (int d = 32; d >= 1; d >>= 1) s += __shfl_xor(s, d, 64);
  if (lane == 0) qv[b * HH + o] = s + Wa_b[o] + Ua_b[o];
}

// ---------------- fused energy GEMM, fp16 operands, 2-phase double-buffer ----------------
// energy[m] += sum_n tanh( (enc[m,:]·Ua[n,:]) + qv[b,n] ) * Va[n]
// 128x128 tile, BK=64, 4 waves (2x2 of 64x64), mfma_f32_16x16x32_f16.
// T3-minimum: STAGE(next) issued BEFORE compute(cur); ONE barrier per K-step
// (its vmcnt/lgkm drain lands after the compute phase covered the load latency).
// Race audit: stage(t+1)->buf^1 never touches buf being read; barrier at end of t
// drains both the prefetch (vmcnt) and the ds_reads (lgkm) before buffers swap.
__global__ __launch_bounds__(256) void energy_gemm_h(const _Float16* __restrict__ Ahp,
                                                     const _Float16* __restrict__ Bh,
                                                     const float* __restrict__ qv,
                                                     const float* __restrict__ Va,
                                                     float* __restrict__ energy) {
  __shared__ __align__(16) _Float16 As[2][128 * 64];
  __shared__ __align__(16) _Float16 Bs[2][128 * 64];

  const int tid  = threadIdx.x;
  const int lane = tid & 63;
  const int w    = tid >> 6;
  const int wrow = (w & 1) * 64;
  const int wcol = (w >> 1) * 64;
  const int lr   = lane & 15;   // row-in-16 (A) / col-in-16 (B)
  const int lq   = lane >> 4;   // k-chunk of 8

  // XCD swizzle: all 8 N-blocks of one M-strip land on the same XCD (A read once)
  const int x     = blockIdx.x;
  const int xcd   = x & 7;
  const int i6    = x >> 3;            // 0..511
  const int strip = xcd * 64 + (i6 >> 3);
  const int nblk  = i6 & 7;
  const int m0    = strip * 128;
  const int n0    = nblk * 128;

  f32x4 acc[4][4];
#pragma unroll
  for (int i = 0; i < 4; ++i)
#pragma unroll
    for (int j = 0; j < 4; ++j) acc[i][j] = (f32x4){0.f, 0.f, 0.f, 0.f};

  // 8 async loads per thread per K-step; xor-swizzled global source, linear LDS
#define STAGE(buf, kt_) do {                                                   \
    const int k0_ = (kt_) * 64;                                                \
    _Pragma("unroll")                                                          \
    for (int i_ = 0; i_ < 4; ++i_) {                                           \
      int g_ = tid + 256 * i_;                                                 \
      int r_ = g_ >> 3;                                                        \
      int c_ = (g_ & 7) ^ (r_ & 7);                                            \
      gload_lds16(Bh + (size_t)(n0 + r_) * HH + k0_ + c_ * 8,                  \
                  &Bs[buf][g_ * 8]);                                           \
      gload_lds16(Ahp + (size_t)(m0 + r_) * HH + k0_ + c_ * 8,                 \
                  &As[buf][g_ * 8]);                                           \
    }                                                                          \
  } while (0)

  STAGE(0, 0);
  __syncthreads();          // drain: tile 0 resident
  int cur = 0;

  for (int kt = 0; kt < 16; ++kt) {
    if (kt + 1 < 16) STAGE(cur ^ 1, kt + 1);   // prefetch overlaps compute below
#pragma unroll
    for (int kk = 0; kk < 2; ++kk) {
      h8 af[4], bf[4];
#pragma unroll
      for (int i = 0; i < 4; ++i) {
        int ra = wrow + i * 16 + lr;
        int ca = kk * 4 + lq;
        af[i] = *(const h8*)&As[cur][(ra * 8 + (ca ^ (ra & 7))) * 8];
        int rb = wcol + i * 16 + lr;
        bf[i] = *(const h8*)&Bs[cur][(rb * 8 + (ca ^ (rb & 7))) * 8];
      }
#pragma unroll
      for (int i = 0; i < 4; ++i)
#pragma unroll
        for (int j = 0; j < 4; ++j)
          acc[i][j] = __builtin_amdgcn_mfma_f32_16x16x32_f16(af[i], bf[j], acc[i][j], 0, 0, 0);
    }
    __syncthreads();        // drains prefetch (vmcnt) + ds_reads (lgkm); swap safe
    cur ^= 1;
  }
#undef STAGE

  // Epilogue: per-row partial energy over this block's 128 columns.
  // C/D layout: col = lane&15, row = (lane>>4)*4 + reg  [dtype-independent, m89/m121]
  const int bq = m0 >> 11;  // 2048 rows per batch; 128-row strip never crosses b
  float qvv[4], vaw[4];
#pragma unroll
  for (int j = 0; j < 4; ++j) {
    int n = n0 + wcol + j * 16 + lr;
    qvv[j] = qv[bq * HH + n];
    vaw[j] = Va[n];
  }
#pragma unroll
  for (int i = 0; i < 4; ++i) {
    float p[4] = {0.f, 0.f, 0.f, 0.f};
#pragma unroll
    for (int j = 0; j < 4; ++j)
#pragma unroll
      for (int r = 0; r < 4; ++r)
        p[r] += fast_tanh(acc[i][j][r] + qvv[j]) * vaw[j];
#pragma unroll
    for (int r = 0; r < 4; ++r) {
      float v = p[r];
      v += __shfl_xor(v, 1, 64);
      v += __shfl_xor(v, 2, 64);
      v += __shfl_xor(v, 4, 64);
      v += __shfl_xor(v, 8, 64);
      if (lr == 0) {
        int m = m0 + wrow + i * 16 + lq * 4 + r;
        atomicAdd(&energy[m], v);
      }
    }
  }
}

// ---------------- fallback: in-kernel convert GEMM (fp32 A, small ws) ----------------
__global__ __launch_bounds__(256) void energy_gemm_f32(const float* __restrict__ Ag,
                                                       const _Float16* __restrict__ Bh,
                                                       const float* __restrict__ qv,
                                                       const float* __restrict__ Va,
                                                       float* __restrict__ energy) {
  __shared__ __align__(16) _Float16 As[128 * 64];
  __shared__ __align__(16) _Float16 Bs[128 * 64];
  const int tid  = threadIdx.x;
  const int lane = tid & 63;
  const int w    = tid >> 6;
  const int wrow = (w & 1) * 64;
  const int wcol = (w >> 1) * 64;
  const int lr   = lane & 15;
  const int lq   = lane >> 4;
  const int x     = blockIdx.x;
  const int xcd   = x & 7;
  const int i6    = x >> 3;
  const int strip = xcd * 64 + (i6 >> 3);
  const int nblk  = i6 & 7;
  const int m0    = strip * 128;
  const int n0    = nblk * 128;
  f32x4 acc[4][4];
#pragma unroll
  for (int i = 0; i < 4; ++i)
#pragma unroll
    for (int j = 0; j < 4; ++j) acc[i][j] = (f32x4){0.f, 0.f, 0.f, 0.f};
  for (int kt = 0; kt < 16; ++kt) {
    const int k0 = kt * 64;
#pragma unroll
    for (int i = 0; i < 4; ++i) {
      int g = tid + 256 * i;
      int r = g >> 3;
      int c = (g & 7) ^ (r & 7);
      gload_lds16(Bh + (size_t)(n0 + r) * HH + k0 + c * 8, &Bs[g * 8]);
    }
    float4 fa[8];
#pragma unroll
    for (int i = 0; i < 4; ++i) {
      int g = tid + 256 * i;
      int r = g >> 3;
      int c = (g & 7) ^ (r & 7);
      const float* src = Ag + (size_t)(m0 + r) * HH + k0 + c * 8;
      fa[2 * i]     = *(const float4*)src;
      fa[2 * i + 1] = *(const float4*)(src + 4);
    }
#pragma unroll
    for (int i = 0; i < 4; ++i) {
      int g = tid + 256 * i;
      h8 v;
      v[0]=(_Float16)fa[2*i].x;   v[1]=(_Float16)fa[2*i].y;
      v[2]=(_Float16)fa[2*i].z;   v[3]=(_Float16)fa[2*i].w;
      v[4]=(_Float16)fa[2*i+1].x; v[5]=(_Float16)fa[2*i+1].y;
      v[6]=(_Float16)fa[2*i+1].z; v[7]=(_Float16)fa[2*i+1].w;
      *(h8*)&As[g * 8] = v;
    }
    __syncthreads();
#pragma unroll
    for (int kk = 0; kk < 2; ++kk) {
      h8 af[4], bf[4];
#pragma unroll
      for (int i = 0; i < 4; ++i) {
        int ra = wrow + i * 16 + lr;
        int ca = kk * 4 + lq;
        af[i] = *(const h8*)&As[(ra * 8 + (ca ^ (ra & 7))) * 8];
        int rb = wcol + i * 16 + lr;
        bf[i] = *(const h8*)&Bs[(rb * 8 + (ca ^ (rb & 7))) * 8];
      }
#pragma unroll
      for (int i = 0; i < 4; ++i)
#pragma unroll
        for (int j = 0; j < 4; ++j)
          acc[i][j] = __builtin_amdgcn_mfma_f32_16x16x32_f16(af[i], bf[j], acc[i][j], 0, 0, 0);
    }
    __syncthreads();
  }
  const int bq = m0 >> 11;
  float qvv[4], vaw[4];
#pragma unroll
  for (int j = 0; j < 4; ++j) {
    int n = n0 + wcol + j * 16 + lr;
    qvv[j] = qv[bq * HH + n];
    vaw[j] = Va[n];
  }
#pragma unroll
  for (int i = 0; i < 4; ++i) {
    float p[4] = {0.f, 0.f, 0.f, 0.f};
#pragma unroll
    for (int j = 0; j < 4; ++j)
#pragma unroll
      for (int r = 0; r < 4; ++r)
        p[r] += fast_tanh(acc[i][j][r] + qvv[j]) * vaw[j];
#pragma unroll
    for (int r = 0; r < 4; ++r) {
      float v = p[r];
      v += __shfl_xor(v, 1, 64);
      v += __shfl_xor(v, 2, 64);
      v += __shfl_xor(v, 4, 64);
      v += __shfl_xor(v, 8, 64);
      if (lr == 0) {
        int m = m0 + wrow + i * 16 + lq * 4 + r;
        atomicAdd(&energy[m], v);
      }
    }
  }
}

// ---------------- sparsemax (bisection): attn + compacted support ----------------
__global__ __launch_bounds__(256) void sparse_k(const float* __restrict__ energy,
                                                const float* __restrict__ Va_b,
                                                float* __restrict__ attn,
                                                int* __restrict__ scnt,
                                                int* __restrict__ ssidx,
                                                float* __restrict__ saval) {
  const int b = blockIdx.x;
  const int tid = threadIdx.x;
  const int lane = tid & 63;
  const int w = tid >> 6;
  __shared__ int cnt;
  if (tid == 0) cnt = 0;

  const float* z = energy + (size_t)b * SS;
  const float vb = Va_b[0];
  float zv[32];
#pragma unroll
  for (int k = 0; k < 32; ++k) zv[k] = z[lane + 64 * k] + vb;

  float mx = zv[0];
#pragma unroll
  for (int k = 1; k < 32; ++k) mx = fmaxf(mx, zv[k]);
#pragma unroll
  for (int d = 32; d >= 1; d >>= 1) mx = fmaxf(mx, __shfl_xor(mx, d, 64));

  // f(tau) = sum(max(z-tau,0)) - 1 has its root in [mx-1, mx]
  float lo = mx - 1.f, hi = mx;
  for (int it = 0; it < 40; ++it) {
    float tau = 0.5f * (lo + hi);
    float ss = 0.f;
#pragma unroll
    for (int k = 0; k < 32; ++k) ss += fmaxf(zv[k] - tau, 0.f);
#pragma unroll
    for (int d = 32; d >= 1; d >>= 1) ss += __shfl_xor(ss, d, 64);
    if (ss >= 1.f) lo = tau; else hi = tau;
  }
  const float tau = 0.5f * (lo + hi);

  __syncthreads();  // cnt=0 visible
  int* si = ssidx + b * SS;
  float* av = saval + b * SS;
#pragma unroll
  for (int kk = 0; kk < 8; ++kk) {
    int k = w * 8 + kk;
    int s = lane + 64 * k;
    float a = fmaxf(zv[k] - tau, 0.f);
    attn[(size_t)b * SS + s] = a;
    if (a > 0.f) {
      int p = atomicAdd(&cnt, 1);
      si[p] = s;
      av[p] = a;
    }
  }
  __syncthreads();
  if (tid == 0) scnt[b] = cnt;
}

// ---------------- sparse context GEMV, parallel over support chunks ----------------
__global__ __launch_bounds__(256) void ctx_k(const float* __restrict__ enc,
                                             const int* __restrict__ scnt,
                                             const int* __restrict__ ssidx,
                                             const float* __restrict__ saval,
                                             float* __restrict__ ctx) {
  const int b = blockIdx.x >> 4;      // /NC
  const int c = blockIdx.x & (NC - 1);
  const int tid = threadIdx.x;
  const int n = scnt[b];
  if (c >= n) return;

  const float* eb = enc + (size_t)b * SS * HH;
  const int* si = ssidx + b * SS;
  const float* av = saval + b * SS;

  float c0 = 0.f, c1 = 0.f, c2 = 0.f, c3 = 0.f;
  for (int p = c; p < n; p += NC) {
    float a = av[p];
    const float* row = eb + (size_t)si[p] * HH;
    c0 += a * row[tid];
    c1 += a * row[tid + 256];
    c2 += a * row[tid + 512];
    c3 += a * row[tid + 768];
  }
  atomicAdd(&ctx[(size_t)b * HH + tid],       c0);
  atomicAdd(&ctx[(size_t)b * HH + tid + 256], c1);
  atomicAdd(&ctx[(size_t)b * HH + tid + 512], c2);
  atomicAdd(&ctx[(size_t)b * HH + tid + 768], c3);
}

extern "C" void kernel_launch(void* const* d_in, const int* in_sizes, int n_in,
                              void* d_out, int out_size, void* d_ws, size_t ws_size,
                              hipStream_t stream) {
  const float* enc  = (const float*)d_in[0];
  const float* dh   = (const float*)d_in[1];
  const float* Wa_w = (const float*)d_in[2];
  const float* Wa_b = (const float*)d_in[3];
  const float* Ua_w = (const float*)d_in[4];
  const float* Ua_b = (const float*)d_in[5];
  const float* Va_w = (const float*)d_in[6];
  const float* Va_b = (const float*)d_in[7];

  float* out_ctx  = (float*)d_out;               // [B,1,H] = 32768 floats
  float* out_attn = (float*)d_out + BB * HH;     // [B,S]   = 65536 floats

  char* ws = (char*)d_ws;
  _Float16* Ua_h = (_Float16*)ws;                                  // 2 MB
  float* qv      = (float*)(ws + 2 * 1024 * 1024);                 // 128 KB
  float* energy  = (float*)(ws + 2 * 1024 * 1024 + 128 * 1024);    // 256 KB
  int*   scnt    = (int*)  (ws + 2 * 1024 * 1024 + 512 * 1024);    // 128 B
  int*   ssidx   = (int*)  (ws + 2 * 1024 * 1024 + 516 * 1024);    // 256 KB
  float* saval   = (float*)(ws + 2 * 1024 * 1024 + 772 * 1024);    // 256 KB
  _Float16* enc_h = (_Float16*)(ws + 4 * 1024 * 1024);             // 128 MB (if it fits)

  const size_t need_h = 4ull * 1024 * 1024 + (size_t)MTOT * HH * sizeof(_Float16);
  const bool use_ah = (ws_size >= need_h);

  if (use_ah) {
    // enc fp32 -> fp16: grid-strided, 16 loads in flight per thread
    cvt_h_big<<<4096, 256, 0, stream>>>(enc, enc_h);
  }
  cvt_h<<<512, 256, 0, stream>>>(Ua_w, Ua_h);     // Ua: 1M elems -> 512 blocks
  query_k<<<8192, 256, 0, stream>>>(dh, Wa_w, Wa_b, Ua_b, qv);
  hipMemsetAsync(energy, 0, MTOT * sizeof(float), stream);
  hipMemsetAsync(out_ctx, 0, BB * HH * sizeof(float), stream);
  if (use_ah) {
    energy_gemm_h<<<4096, 256, 0, stream>>>(enc_h, Ua_h, qv, Va_w, energy);
  } else {
    energy_gemm_f32<<<4096, 256, 0, stream>>>(enc, Ua_h, qv, Va_w, energy);
  }
  sparse_k<<<BB, 256, 0, stream>>>(energy, Va_b, out_attn, scnt, ssidx, saval);
  ctx_k<<<BB * NC, 256, 0, stream>>>(enc, scnt, ssidx, saval, out_ctx);
}

// Round 6
// 617.529 us; speedup vs baseline: 1.0925x; 1.0925x over previous
//
#include <hip/hip_runtime.h>
#include <stdint.h>
#include <stddef.h>

#define BB 32
#define SS 2048
#define HH 1024
#define MTOT (BB*SS)   // 65536
#define NC 16          // context chunks per batch

typedef _Float16 h8 __attribute__((ext_vector_type(8)));
typedef float f32x4 __attribute__((ext_vector_type(4)));

__device__ __forceinline__ void gload_lds16(const void* g, void* l) {
  __builtin_amdgcn_global_load_lds(
      (const __attribute__((address_space(1))) void*)g,
      (__attribute__((address_space(3))) void*)l,
      16, 0, 0);
}

__device__ __forceinline__ float fast_tanh(float x) {
  x = fminf(15.f, fmaxf(-15.f, x));
  float t = __expf(2.f * x);
  return (t - 1.f) * __builtin_amdgcn_rcpf(t + 1.f);
}

// ---------------- fp32 -> fp16 streaming convert (8 elems/thread) ----------------
__global__ __launch_bounds__(256) void cvt_h(const float* __restrict__ src,
                                             _Float16* __restrict__ dst) {
  int t = blockIdx.x * 256 + threadIdx.x;
  const float4* s4 = (const float4*)src + (size_t)t * 2;
  float4 f0 = s4[0], f1 = s4[1];
  h8 v;
  v[0]=(_Float16)f0.x; v[1]=(_Float16)f0.y; v[2]=(_Float16)f0.z; v[3]=(_Float16)f0.w;
  v[4]=(_Float16)f1.x; v[5]=(_Float16)f1.y; v[6]=(_Float16)f1.z; v[7]=(_Float16)f1.w;
  *(h8*)(dst + (size_t)t * 8) = v;
}

// ---------------- qv[b,o] = dh[b,:]·Wa[o,:] + Wa_b[o] + Ua_b[o] ----------------
__global__ __launch_bounds__(256) void query_k(const float* __restrict__ dh,
                                               const float* __restrict__ Wa,
                                               const float* __restrict__ Wa_b,
                                               const float* __restrict__ Ua_b,
                                               float* __restrict__ qv) {
  int gw = (blockIdx.x * 256 + threadIdx.x) >> 6;   // wave id, 32768 total
  int lane = threadIdx.x & 63;
  int o = gw >> 5;                                  // o-major: Wa row reused by 32 waves
  int b = gw & 31;
  const float4* x4 = (const float4*)(dh + (size_t)b * HH);
  const float4* w4 = (const float4*)(Wa + (size_t)o * HH);
  float s = 0.f;
#pragma unroll
  for (int j = 0; j < 4; ++j) {
    float4 a = x4[lane + 64 * j];
    float4 c = w4[lane + 64 * j];
    s += a.x * c.x + a.y * c.y + a.z * c.z + a.w * c.w;
  }
#pragma unroll
  for (int d = 32; d >= 1; d >>= 1) s += __shfl_xor(s, d, 64);
  if (lane == 0) qv[b * HH + o] = s + Wa_b[o] + Ua_b[o];
}

// ---------------- fused energy GEMM, fp16 operands, m97 geometry ----------------
// energy[m] += sum_n tanh( (enc[m,:]·Ua[n,:]) + qv[b,n] ) * Va[n]
// 128x128 tile, BK=32 (m97-exact shape: 16 KiB LDS, 4 staging loads/thread/step,
// 16 MFMA + 8 ds_read_b128 per barrier-pair), 4 waves (2x2 of 64x64).
// Single-buffer, 2 barriers/step — the verified-best structure at this tile size.
__global__ __launch_bounds__(256) void energy_gemm_h(const _Float16* __restrict__ Ahp,
                                                     const _Float16* __restrict__ Bh,
                                                     const float* __restrict__ qv,
                                                     const float* __restrict__ Va,
                                                     float* __restrict__ energy) {
  __shared__ __align__(16) _Float16 As[128 * 32];   // 8 KB
  __shared__ __align__(16) _Float16 Bs[128 * 32];   // 8 KB

  const int tid  = threadIdx.x;
  const int lane = tid & 63;
  const int w    = tid >> 6;
  const int wrow = (w & 1) * 64;
  const int wcol = (w >> 1) * 64;
  const int lr   = lane & 15;   // row-in-16 (A) / col-in-16 (B)
  const int lq   = lane >> 4;   // k-chunk of 8 (0..3)

  // XCD swizzle: all 8 N-blocks of one M-strip land on the same XCD (A read once)
  const int x     = blockIdx.x;
  const int xcd   = x & 7;
  const int i6    = x >> 3;            // 0..511
  const int strip = xcd * 64 + (i6 >> 3);
  const int nblk  = i6 & 7;
  const int m0    = strip * 128;
  const int n0    = nblk * 128;

  f32x4 acc[4][4];
#pragma unroll
  for (int i = 0; i < 4; ++i)
#pragma unroll
    for (int j = 0; j < 4; ++j) acc[i][j] = (f32x4){0.f, 0.f, 0.f, 0.f};

  // Staging geometry: 512 chunks (16B) per operand tile, 2 per thread.
  // Chunk slot g stores logical k-chunk c = (g&3) ^ ((r>>1)&3)  (r = g>>2).
  // Bank map for readers: 16(r&1) + 4*(lq^((r>>1)&3)) -> 8 distinct slots per
  // 8 rows -> 2-way aliasing only (free, m136).
  const int g0 = tid;
  const int g1 = tid + 256;
  const int r0 = g0 >> 2, c0 = (g0 & 3) ^ ((r0 >> 1) & 3);
  const int r1 = g1 >> 2, c1 = (g1 & 3) ^ ((r1 >> 1) & 3);
  // hoisted, pointer-incremented sources (+32 fp16 = +64 B per K-step)
  const _Float16* ap0 = Ahp + (size_t)(m0 + r0) * HH + c0 * 8;
  const _Float16* ap1 = Ahp + (size_t)(m0 + r1) * HH + c1 * 8;
  const _Float16* bp0 = Bh  + (size_t)(n0 + r0) * HH + c0 * 8;
  const _Float16* bp1 = Bh  + (size_t)(n0 + r1) * HH + c1 * 8;

  for (int kt = 0; kt < 32; ++kt) {
    // A first (L3-resident workspace, longer latency), then B (L2-hot)
    gload_lds16(ap0, &As[g0 * 8]);
    gload_lds16(ap1, &As[g1 * 8]);
    gload_lds16(bp0, &Bs[g0 * 8]);
    gload_lds16(bp1, &Bs[g1 * 8]);
    __syncthreads();   // drains vmcnt: tile resident

    h8 af[4], bf[4];
#pragma unroll
    for (int i = 0; i < 4; ++i) {
      int ra = wrow + i * 16 + lr;
      af[i] = *(const h8*)&As[(ra * 4 + (lq ^ ((ra >> 1) & 3))) * 8];
      int rb = wcol + i * 16 + lr;
      bf[i] = *(const h8*)&Bs[(rb * 4 + (lq ^ ((rb >> 1) & 3))) * 8];
    }
#pragma unroll
    for (int i = 0; i < 4; ++i)
#pragma unroll
      for (int j = 0; j < 4; ++j)
        acc[i][j] = __builtin_amdgcn_mfma_f32_16x16x32_f16(af[i], bf[j], acc[i][j], 0, 0, 0);
    __syncthreads();   // reads done; next stage may overwrite
    ap0 += 32; ap1 += 32; bp0 += 32; bp1 += 32;
  }

  // Epilogue: per-row partial energy over this block's 128 columns.
  // C/D layout: col = lane&15, row = (lane>>4)*4 + reg  [dtype-independent, m89/m121]
  const int bq = m0 >> 11;  // 2048 rows per batch; 128-row strip never crosses b
  float qvv[4], vaw[4];
#pragma unroll
  for (int j = 0; j < 4; ++j) {
    int n = n0 + wcol + j * 16 + lr;
    qvv[j] = qv[bq * HH + n];
    vaw[j] = Va[n];
  }
#pragma unroll
  for (int i = 0; i < 4; ++i) {
    float p[4] = {0.f, 0.f, 0.f, 0.f};
#pragma unroll
    for (int j = 0; j < 4; ++j)
#pragma unroll
      for (int r = 0; r < 4; ++r)
        p[r] += fast_tanh(acc[i][j][r] + qvv[j]) * vaw[j];
#pragma unroll
    for (int r = 0; r < 4; ++r) {
      float v = p[r];
      v += __shfl_xor(v, 1, 64);
      v += __shfl_xor(v, 2, 64);
      v += __shfl_xor(v, 4, 64);
      v += __shfl_xor(v, 8, 64);
      if (lr == 0) {
        int m = m0 + wrow + i * 16 + lq * 4 + r;
        atomicAdd(&energy[m], v);
      }
    }
  }
}

// ---------------- fallback: in-kernel convert GEMM (fp32 A, small ws) ----------------
__global__ __launch_bounds__(256) void energy_gemm_f32(const float* __restrict__ Ag,
                                                       const _Float16* __restrict__ Bh,
                                                       const float* __restrict__ qv,
                                                       const float* __restrict__ Va,
                                                       float* __restrict__ energy) {
  __shared__ __align__(16) _Float16 As[128 * 64];
  __shared__ __align__(16) _Float16 Bs[128 * 64];
  const int tid  = threadIdx.x;
  const int lane = tid & 63;
  const int w    = tid >> 6;
  const int wrow = (w & 1) * 64;
  const int wcol = (w >> 1) * 64;
  const int lr   = lane & 15;
  const int lq   = lane >> 4;
  const int x     = blockIdx.x;
  const int xcd   = x & 7;
  const int i6    = x >> 3;
  const int strip = xcd * 64 + (i6 >> 3);
  const int nblk  = i6 & 7;
  const int m0    = strip * 128;
  const int n0    = nblk * 128;
  f32x4 acc[4][4];
#pragma unroll
  for (int i = 0; i < 4; ++i)
#pragma unroll
    for (int j = 0; j < 4; ++j) acc[i][j] = (f32x4){0.f, 0.f, 0.f, 0.f};
  for (int kt = 0; kt < 16; ++kt) {
    const int k0 = kt * 64;
#pragma unroll
    for (int i = 0; i < 4; ++i) {
      int g = tid + 256 * i;
      int r = g >> 3;
      int c = (g & 7) ^ (r & 7);
      gload_lds16(Bh + (size_t)(n0 + r) * HH + k0 + c * 8, &Bs[g * 8]);
    }
    float4 fa[8];
#pragma unroll
    for (int i = 0; i < 4; ++i) {
      int g = tid + 256 * i;
      int r = g >> 3;
      int c = (g & 7) ^ (r & 7);
      const float* src = Ag + (size_t)(m0 + r) * HH + k0 + c * 8;
      fa[2 * i]     = *(const float4*)src;
      fa[2 * i + 1] = *(const float4*)(src + 4);
    }
#pragma unroll
    for (int i = 0; i < 4; ++i) {
      int g = tid + 256 * i;
      h8 v;
      v[0]=(_Float16)fa[2*i].x;   v[1]=(_Float16)fa[2*i].y;
      v[2]=(_Float16)fa[2*i].z;   v[3]=(_Float16)fa[2*i].w;
      v[4]=(_Float16)fa[2*i+1].x; v[5]=(_Float16)fa[2*i+1].y;
      v[6]=(_Float16)fa[2*i+1].z; v[7]=(_Float16)fa[2*i+1].w;
      *(h8*)&As[g * 8] = v;
    }
    __syncthreads();
#pragma unroll
    for (int kk = 0; kk < 2; ++kk) {
      h8 af[4], bf[4];
#pragma unroll
      for (int i = 0; i < 4; ++i) {
        int ra = wrow + i * 16 + lr;
        int ca = kk * 4 + lq;
        af[i] = *(const h8*)&As[(ra * 8 + (ca ^ (ra & 7))) * 8];
        int rb = wcol + i * 16 + lr;
        bf[i] = *(const h8*)&Bs[(rb * 8 + (ca ^ (rb & 7))) * 8];
      }
#pragma unroll
      for (int i = 0; i < 4; ++i)
#pragma unroll
        for (int j = 0; j < 4; ++j)
          acc[i][j] = __builtin_amdgcn_mfma_f32_16x16x32_f16(af[i], bf[j], acc[i][j], 0, 0, 0);
    }
    __syncthreads();
  }
  const int bq = m0 >> 11;
  float qvv[4], vaw[4];
#pragma unroll
  for (int j = 0; j < 4; ++j) {
    int n = n0 + wcol + j * 16 + lr;
    qvv[j] = qv[bq * HH + n];
    vaw[j] = Va[n];
  }
#pragma unroll
  for (int i = 0; i < 4; ++i) {
    float p[4] = {0.f, 0.f, 0.f, 0.f};
#pragma unroll
    for (int j = 0; j < 4; ++j)
#pragma unroll
      for (int r = 0; r < 4; ++r)
        p[r] += fast_tanh(acc[i][j][r] + qvv[j]) * vaw[j];
#pragma unroll
    for (int r = 0; r < 4; ++r) {
      float v = p[r];
      v += __shfl_xor(v, 1, 64);
      v += __shfl_xor(v, 2, 64);
      v += __shfl_xor(v, 4, 64);
      v += __shfl_xor(v, 8, 64);
      if (lr == 0) {
        int m = m0 + wrow + i * 16 + lq * 4 + r;
        atomicAdd(&energy[m], v);
      }
    }
  }
}

// ---------------- sparsemax (bisection): attn + compacted support ----------------
__global__ __launch_bounds__(256) void sparse_k(const float* __restrict__ energy,
                                                const float* __restrict__ Va_b,
                                                float* __restrict__ attn,
                                                int* __restrict__ scnt,
                                                int* __restrict__ ssidx,
                                                float* __restrict__ saval) {
  const int b = blockIdx.x;
  const int tid = threadIdx.x;
  const int lane = tid & 63;
  const int w = tid >> 6;
  __shared__ int cnt;
  if (tid == 0) cnt = 0;

  const float* z = energy + (size_t)b * SS;
  const float vb = Va_b[0];
  float zv[32];
#pragma unroll
  for (int k = 0; k < 32; ++k) zv[k] = z[lane + 64 * k] + vb;

  float mx = zv[0];
#pragma unroll
  for (int k = 1; k < 32; ++k) mx = fmaxf(mx, zv[k]);
#pragma unroll
  for (int d = 32; d >= 1; d >>= 1) mx = fmaxf(mx, __shfl_xor(mx, d, 64));

  // f(tau) = sum(max(z-tau,0)) - 1 has its root in [mx-1, mx]
  float lo = mx - 1.f, hi = mx;
  for (int it = 0; it < 40; ++it) {
    float tau = 0.5f * (lo + hi);
    float ss = 0.f;
#pragma unroll
    for (int k = 0; k < 32; ++k) ss += fmaxf(zv[k] - tau, 0.f);
#pragma unroll
    for (int d = 32; d >= 1; d >>= 1) ss += __shfl_xor(ss, d, 64);
    if (ss >= 1.f) lo = tau; else hi = tau;
  }
  const float tau = 0.5f * (lo + hi);

  __syncthreads();  // cnt=0 visible
  int* si = ssidx + b * SS;
  float* av = saval + b * SS;
#pragma unroll
  for (int kk = 0; kk < 8; ++kk) {
    int k = w * 8 + kk;
    int s = lane + 64 * k;
    float a = fmaxf(zv[k] - tau, 0.f);
    attn[(size_t)b * SS + s] = a;
    if (a > 0.f) {
      int p = atomicAdd(&cnt, 1);
      si[p] = s;
      av[p] = a;
    }
  }
  __syncthreads();
  if (tid == 0) scnt[b] = cnt;
}

// ---------------- sparse context GEMV, parallel over support chunks ----------------
__global__ __launch_bounds__(256) void ctx_k(const float* __restrict__ enc,
                                             const int* __restrict__ scnt,
                                             const int* __restrict__ ssidx,
                                             const float* __restrict__ saval,
                                             float* __restrict__ ctx) {
  const int b = blockIdx.x >> 4;      // /NC
  const int c = blockIdx.x & (NC - 1);
  const int tid = threadIdx.x;
  const int n = scnt[b];
  if (c >= n) return;

  const float* eb = enc + (size_t)b * SS * HH;
  const int* si = ssidx + b * SS;
  const float* av = saval + b * SS;

  float c0 = 0.f, c1 = 0.f, c2 = 0.f, c3 = 0.f;
  for (int p = c; p < n; p += NC) {
    float a = av[p];
    const float* row = eb + (size_t)si[p] * HH;
    c0 += a * row[tid];
    c1 += a * row[tid + 256];
    c2 += a * row[tid + 512];
    c3 += a * row[tid + 768];
  }
  atomicAdd(&ctx[(size_t)b * HH + tid],       c0);
  atomicAdd(&ctx[(size_t)b * HH + tid + 256], c1);
  atomicAdd(&ctx[(size_t)b * HH + tid + 512], c2);
  atomicAdd(&ctx[(size_t)b * HH + tid + 768], c3);
}

extern "C" void kernel_launch(void* const* d_in, const int* in_sizes, int n_in,
                              void* d_out, int out_size, void* d_ws, size_t ws_size,
                              hipStream_t stream) {
  const float* enc  = (const float*)d_in[0];
  const float* dh   = (const float*)d_in[1];
  const float* Wa_w = (const float*)d_in[2];
  const float* Wa_b = (const float*)d_in[3];
  const float* Ua_w = (const float*)d_in[4];
  const float* Ua_b = (const float*)d_in[5];
  const float* Va_w = (const float*)d_in[6];
  const float* Va_b = (const float*)d_in[7];

  float* out_ctx  = (float*)d_out;               // [B,1,H] = 32768 floats
  float* out_attn = (float*)d_out + BB * HH;     // [B,S]   = 65536 floats

  char* ws = (char*)d_ws;
  _Float16* Ua_h = (_Float16*)ws;                                  // 2 MB
  float* qv      = (float*)(ws + 2 * 1024 * 1024);                 // 128 KB
  float* energy  = (float*)(ws + 2 * 1024 * 1024 + 128 * 1024);    // 256 KB
  int*   scnt    = (int*)  (ws + 2 * 1024 * 1024 + 512 * 1024);    // 128 B
  int*   ssidx   = (int*)  (ws + 2 * 1024 * 1024 + 516 * 1024);    // 256 KB
  float* saval   = (float*)(ws + 2 * 1024 * 1024 + 772 * 1024);    // 256 KB
  _Float16* enc_h = (_Float16*)(ws + 4 * 1024 * 1024);             // 128 MB (if it fits)

  const size_t need_h = 4ull * 1024 * 1024 + (size_t)MTOT * HH * sizeof(_Float16);
  const bool use_ah = (ws_size >= need_h);

  // small kernels first; enc conversion LAST so its fp16 image is freshest
  // in L3 when the GEMM reads it
  cvt_h<<<512, 256, 0, stream>>>(Ua_w, Ua_h);     // Ua: 1M elems -> 512 blocks
  query_k<<<8192, 256, 0, stream>>>(dh, Wa_w, Wa_b, Ua_b, qv);
  hipMemsetAsync(energy, 0, MTOT * sizeof(float), stream);
  hipMemsetAsync(out_ctx, 0, BB * HH * sizeof(float), stream);
  if (use_ah) {
    cvt_h<<<32768, 256, 0, stream>>>(enc, enc_h);
    energy_gemm_h<<<4096, 256, 0, stream>>>(enc_h, Ua_h, qv, Va_w, energy);
  } else {
    energy_gemm_f32<<<4096, 256, 0, stream>>>(enc, Ua_h, qv, Va_w, energy);
  }
  sparse_k<<<BB, 256, 0, stream>>>(energy, Va_b, out_attn, scnt, ssidx, saval);
  ctx_k<<<BB * NC, 256, 0, stream>>>(enc, scnt, ssidx, saval, out_ctx);
}